// Round 9
// baseline (7953.305 us; speedup 1.0000x reference)
//
#include <hip/hip_runtime.h>
#include <hip/hip_fp16.h>
#include <stdint.h>

// Problem constants
#define BB 64
#define SS 512
#define EE 128
#define HH 256
#define KK 20
#define NEGV -9999.0f
#define SOS_IDX 19

typedef unsigned int u32;
typedef _Float16 half8 __attribute__((ext_vector_type(8)));
typedef float f32x4 __attribute__((ext_vector_type(4)));
union U4H8 { uint4 u; half8 h; };

__device__ __forceinline__ float sigm(float x){ return 1.0f / (1.0f + __expf(-x)); }
__device__ __forceinline__ float tanh_fast(float x){
  float e = __expf(2.f * x);
  return 1.f - 2.f / (e + 1.f);
}

// ---- K0a: pack W_hh into MFMA B-fragment order, f16.
// B[k][n] = W_hh[orig_row(n)][k], n interleaved: n = 4*unit + gate, orig_row = gate*256 + unit.
// Fragment for v_mfma_f32_16x16x32_f16: lane l holds n = nt*16 + (l&15), k = kf*32 + (l>>4)*8 + j (j=0..7).
// bp[((d*64 + nt)*8 + kf)*64 + l][8] — one uint4 (8 f16) per (d,nt,kf,l) = per id.
__global__ void prep_whh_mfma(const float* __restrict__ whh_f, const float* __restrict__ whh_b,
                              __half* __restrict__ bp){
  int id = blockIdx.x * 256 + threadIdx.x;      // 2*64*8*64 = 65536
  if (id >= 65536) return;
  int l  = id & 63;
  int kf = (id >> 6) & 7;
  int nt = (id >> 9) & 63;
  int d  = (id >> 15) & 1;
  const float* w = d ? whh_b : whh_f;
  int n = nt * 16 + (l & 15);
  int orig_row = (n & 3) * 256 + (n >> 2);
  int kbase = kf * 32 + (l >> 4) * 8;
  __half tmp[8];
  #pragma unroll
  for (int j = 0; j < 8; j++) tmp[j] = __float2half(w[orig_row * 256 + kbase + j]);
  ((uint4*)bp)[id] = *(const uint4*)tmp;
}

// ---- K0b: transpose W_ih -> wt[k(128)][2048] f32 (cols 0..1023 fwd, 1024..2047 bwd)
__global__ void prep_wih(const float* __restrict__ wih_f, const float* __restrict__ wih_b,
                         float* __restrict__ wt){
  int id = blockIdx.x * 256 + threadIdx.x;      // 2*1024*128 = 262144
  if (id >= 262144) return;
  int d = id >> 17;
  int rem = id & 131071;
  int col = rem >> 7;
  int k = rem & 127;
  const float* w = d ? wih_b : wih_f;
  wt[(size_t)k * 2048 + d * 1024 + col] = w[col * 128 + k];
}

// ---- K1: xg = embed[word] @ W_ih.T + b, both dirs, stored f16 (orig col order gate*256+u).
__global__ __launch_bounds__(256) void xg_gemm(const int* __restrict__ word_seq,
    const int* __restrict__ lengths,
    const float* __restrict__ embed, const float* __restrict__ wt,
    const float* __restrict__ b_f, const float* __restrict__ b_b,
    __half* __restrict__ xg){
  __shared__ __align__(16) float xs[16][128];
  int rb = blockIdx.x >> 1, cb = blockIdx.x & 1;
  {
    int s0 = (rb * 16) & 511, bq = (rb * 16) >> 9;
    if (s0 >= lengths[bq]) return;
  }
  int tid = threadIdx.x;
  {
    int r = tid >> 4, kq = (tid & 15) * 8;
    int bs = rb * 16 + r;
    int w = word_seq[bs];
    const float* er = embed + (size_t)w * 128 + kq;
    float4 a = *(const float4*)er;
    float4 b = *(const float4*)(er + 4);
    *(float4*)&xs[r][kq] = a;
    *(float4*)&xs[r][kq + 4] = b;
  }
  __syncthreads();
  int co = tid * 4;
  const float* bias = cb ? b_b : b_f;
  float4 bv = *(const float4*)(bias + co);
  float4 acc[16];
  #pragma unroll
  for (int r = 0; r < 16; r++) acc[r] = bv;
  const float* wptr = wt + cb * 1024 + co;
  for (int k = 0; k < 128; k++){
    float4 w4 = *(const float4*)(wptr + (size_t)k * 2048);
    #pragma unroll
    for (int r = 0; r < 16; r++){
      float xv = xs[r][k];
      acc[r].x += xv * w4.x; acc[r].y += xv * w4.y;
      acc[r].z += xv * w4.z; acc[r].w += xv * w4.w;
    }
  }
  __half* base = xg + (size_t)cb * ((size_t)BB * SS * 1024);
  #pragma unroll
  for (int r = 0; r < 16; r++){
    int bs = rb * 16 + r;
    __half* o = base + (size_t)bs * 1024 + co;
    __half2 p0 = __floats2half2_rn(acc[r].x, acc[r].y);
    __half2 p1 = __floats2half2_rn(acc[r].z, acc[r].w);
    uint2 st; st.x = *(u32*)&p0; st.y = *(u32*)&p1;
    *(uint2*)o = st;
  }
}

// ---- K2: MFMA-batched LSTM. grid=8: bx -> d = bx&1, grp = bx>>1 (16 batches each).
// 512 thr = 8 waves; wave w owns N-tiles nt = w*8 + i (i<8), each 16 gate-cols.
// A (h, M=16 x K=256) from LDS dbuf (XOR-swizzled [m][k] f16); B (W) streamed from L2
// in prepacked fragment order; C prefilled with xg -> D = h@W + xg via 8 chained MFMAs.
// Epilogue: lane = (n, 4 batches). gate = l&3; gates of a unit sit in 4 adjacent lanes
// -> 3 shfl_xor gathers (valid at gate-0 lanes); c-state in gate-0 lanes; h transposed
// 4x4 cross-lane (2-phase butterfly) -> one ds_write_b64 per tile. rnn stored coalesced
// from LDS at top of next iteration. ONE barrier/step. Inactive batches evolve freely
// (bounded garbage, never stored/read downstream).
__global__ __launch_bounds__(512, 2) void lstm_mfma(const int* __restrict__ lengths,
    const __half* __restrict__ bp, const __half* __restrict__ xg,
    __half* __restrict__ rnn){
  __shared__ __align__(16) unsigned char hbuf[2][8192];   // [m(16)][k(256)] f16, swizzled
  int bx = blockIdx.x;
  int d = bx & 1, grp = bx >> 1;
  int tid = threadIdx.x;
  int w = tid >> 6, l = tid & 63;
  int e  = l & 3;          // gate index of this lane's column
  int G  = l >> 4;         // M-row group (batches G*4..G*4+3)
  int nl = l & 15;         // col within tile
  int ui = nl >> 2;        // unit index within 4-lane group

  // zero h buffer 0
  {
    uint4 z; z.x = z.y = z.z = z.w = 0;
    ((uint4*)hbuf[0])[tid] = z;
  }
  // lengths
  int len_r[4];
  #pragma unroll
  for (int r = 0; r < 4; r++) len_r[r] = lengths[grp * 16 + G * 4 + r];
  int lmax = max(max(len_r[0], len_r[1]), max(len_r[2], len_r[3]));
  lmax = max(lmax, __shfl_xor(lmax, 16));
  lmax = max(lmax, __shfl_xor(lmax, 32));
  // store-phase mapping: thread -> (batch ms, 16B-slice j16)
  int ms = tid >> 5, j16 = tid & 31;
  int len_s = lengths[grp * 16 + ms];

  float c[8][4];
  #pragma unroll
  for (int i = 0; i < 8; i++)
    #pragma unroll
    for (int r = 0; r < 4; r++) c[i][r] = 0.f;

  float nsc = (e == 2) ? 2.f : 1.f;       // tanh via 2*sigm(2x)-1 for gate g
  float nmu = nsc;
  float nad = (e == 2) ? -1.f : 0.f;

  const __half* xgd = xg + (size_t)d * BB * SS * 1024;
  const __half* bpd = bp + (size_t)d * 262144;
  __half* rnnd = rnn + d * 256;
  int cur = 0;
  __syncthreads();

  for (int t = 0; t < lmax; t++){
    // store h_{t-1} to rnn (coalesced from LDS)
    if (t > 0){
      int tt = t - 1;
      if (tt < len_s){
        int s = d ? (len_s - 1 - tt) : tt;
        uint4 v = *(const uint4*)(hbuf[cur] + ((ms * 512 + j16 * 16) ^ ((ms & 7) << 4)));
        *(uint4*)(rnnd + ((size_t)(grp * 16 + ms) * 512 + s) * 512 + j16 * 8) = v;
      }
    }
    // A-fragments: lane l -> A[m = nl][k = kf*32 + G*8 + j]
    U4H8 a[8];
    #pragma unroll
    for (int kf = 0; kf < 8; kf++)
      a[kf].u = *(const uint4*)(hbuf[cur] + ((nl * 512 + kf * 64 + G * 16) ^ ((nl & 7) << 4)));
    // xg row bases for this step (per M-row r)
    int sbase[4];
    #pragma unroll
    for (int r = 0; r < 4; r++){
      int s = d ? (len_r[r] - 1 - t) : t;
      s = min(max(s, 0), SS - 1);
      sbase[r] = ((grp * 16 + G * 4 + r) * 512 + s) * 1024;
    }
    #pragma unroll
    for (int i = 0; i < 8; i++){
      int nt = w * 8 + i;
      int col = e * 256 + nt * 4 + ui;       // orig xg column for this lane's n
      f32x4 acc;
      #pragma unroll
      for (int r = 0; r < 4; r++) acc[r] = __half2float(xgd[sbase[r] + col]);
      const __half* bt = bpd + (size_t)nt * 4096;
      #pragma unroll
      for (int kf = 0; kf < 8; kf++){
        U4H8 bf;
        bf.u = *(const uint4*)(bt + kf * 512 + l * 8);
        acc = __builtin_amdgcn_mfma_f32_16x16x32_f16(a[kf].h, bf.h, acc, 0, 0, 0);
      }
      // nonlinearity (per-lane gate), then gather 4 gates into gate-0 lanes
      float gv[4], v1[4], v2[4], v3[4], ht[4];
      #pragma unroll
      for (int r = 0; r < 4; r++) gv[r] = nmu * sigm(nsc * acc[r]) + nad;
      #pragma unroll
      for (int r = 0; r < 4; r++){ v1[r] = __shfl_xor(gv[r], 1); v2[r] = __shfl_xor(gv[r], 2); }
      #pragma unroll
      for (int r = 0; r < 4; r++) v3[r] = __shfl_xor(v1[r], 2);
      // at e==0: i=gv, f=v1, g=v2, o=v3 (garbage elsewhere, harmless)
      #pragma unroll
      for (int r = 0; r < 4; r++){
        float cn = v1[r] * c[i][r] + gv[r] * v2[r];
        c[i][r] = cn;
        ht[r] = v3[r] * tanh_fast(cn);
      }
      // 4x4 transpose across lanes {l, l^4, l^8, l^12}: (unit, batch) -> (batch, unit)
      float aT[4], y[4];
      #pragma unroll
      for (int r = 0; r < 4; r++){
        float rc = __shfl_xor(ht[r ^ 1], 4);
        aT[r] = ((r & 1) == (ui & 1)) ? ht[r] : rc;
      }
      #pragma unroll
      for (int r = 0; r < 4; r++){
        float rc = __shfl_xor(aT[r ^ 2], 8);
        y[r] = ((r & 2) == (ui & 2)) ? aT[r] : rc;
      }
      if (e == 0){
        int mb = G * 4 + ui;                 // batch row
        __half2 p0 = __floats2half2_rn(y[0], y[1]);
        __half2 p1 = __floats2half2_rn(y[2], y[3]);
        uint2 pk; pk.x = *(u32*)&p0; pk.y = *(u32*)&p1;
        *(uint2*)(hbuf[cur ^ 1] + ((mb * 512 + nt * 8) ^ ((mb & 7) << 4))) = pk;
      }
    }
    __syncthreads();
    cur ^= 1;
  }
  // final store: h_{lmax-1}
  if (lmax > 0){
    int tt = lmax - 1;
    if (tt < len_s){
      int s = d ? (len_s - 1 - tt) : tt;
      uint4 v = *(const uint4*)(hbuf[cur] + ((ms * 512 + j16 * 16) ^ ((ms & 7) << 4)));
      *(uint4*)(rnnd + ((size_t)(grp * 16 + ms) * 512 + s) * 512 + j16 * 8) = v;
    }
  }
}

// ---- K3: feats = rnn_out @ lin_W.T + lin_b  (one thread per (row,col)), rnn f16.
__global__ void feat_gemv(const int* __restrict__ lengths,
    const __half* __restrict__ rnn,
    const float* __restrict__ linW, const float* __restrict__ linb,
    float* __restrict__ feats){
  int id = blockIdx.x * 256 + threadIdx.x;
  if (id >= BB * SS * KK) return;
  int row = id / 20;
  int col = id - row * 20;
  int s = row & 511, bq = row >> 9;
  if (s >= lengths[bq]) return;
  const __half* rr = rnn + (size_t)row * 512;
  const float* wr = linW + col * 512;
  float acc = linb[col];
  for (int k8 = 0; k8 < 64; k8++){
    uint4 rv = *(const uint4*)(rr + k8 * 8);
    const __half2* h2 = (const __half2*)&rv;
    float2 p0 = __half22float2(h2[0]);
    float2 p1 = __half22float2(h2[1]);
    float2 p2 = __half22float2(h2[2]);
    float2 p3 = __half22float2(h2[3]);
    float4 wa = *(const float4*)(wr + k8 * 8);
    float4 wb = *(const float4*)(wr + k8 * 8 + 4);
    acc += p0.x * wa.x + p0.y * wa.y + p1.x * wa.z + p1.y * wa.w
         + p2.x * wb.x + p2.y * wb.y + p3.x * wb.z + p3.y * wb.w;
  }
  feats[id] = acc;
}

// ---- K4: CRF numerator + forward scan. One WG = ONE WAVE per batch.
__global__ __launch_bounds__(64) void crf_kernel(const int* __restrict__ tags,
    const int* __restrict__ lengths, const float* __restrict__ trans,
    const float* __restrict__ feats, float* __restrict__ out){
  int b = blockIdx.x, tid = threadIdx.x;
  __shared__ float tr[400];
  __shared__ float sc[20];
  for (int i = tid; i < 400; i += 64) tr[i] = trans[i];
  __syncthreads();
  int l = lengths[b];
  const int* tg = tags + b * SS;
  const float* fb = feats + (size_t)b * SS * 20;
  float p = 0.f;
  for (int s = tid; s < SS; s += 64){
    if (s < l){
      int cur = tg[s];
      int prev = s ? tg[s - 1] : SOS_IDX;
      p += fb[s * 20 + cur] + tr[cur * 20 + prev];
    }
  }
  #pragma unroll
  for (int off = 32; off; off >>= 1) p += __shfl_down(p, off);
  if (tid < 20) sc[tid] = (tid == SOS_IDX) ? 0.f : NEGV;
  float em = (tid < 20 && l > 0) ? fb[tid] : 0.f;
  for (int s = 0; s < l; s++){
    float em_nxt = (tid < 20 && (s + 1) < l) ? fb[(s + 1) * 20 + tid] : 0.f;
    if (tid < 20){
      const float* trow = &tr[tid * 20];
      float v[20];
      float m = -1e30f;
      #pragma unroll
      for (int jj = 0; jj < 20; jj++){ v[jj] = sc[jj] + trow[jj]; m = fmaxf(m, v[jj]); }
      float ssum = 0.f;
      #pragma unroll
      for (int jj = 0; jj < 20; jj++) ssum += __expf(v[jj] - m);
      sc[tid] = em + m + __logf(ssum);
    }
    em = em_nxt;
  }
  if (tid == 0){
    float m = -1e30f;
    #pragma unroll
    for (int i = 0; i < 20; i++) m = fmaxf(m, sc[i]);
    float ssum = 0.f;
    #pragma unroll
    for (int i = 0; i < 20; i++) ssum += __expf(sc[i] - m);
    out[b] = (m + __logf(ssum)) - p;
  }
}

extern "C" void kernel_launch(void* const* d_in, const int* in_sizes, int n_in,
                              void* d_out, int out_size, void* d_ws, size_t ws_size,
                              hipStream_t stream){
  const int*   word_seq = (const int*)d_in[0];
  const int*   tags     = (const int*)d_in[1];
  const int*   lengths  = (const int*)d_in[2];
  const float* embed    = (const float*)d_in[3];
  const float* wih_f    = (const float*)d_in[4];
  const float* whh_f    = (const float*)d_in[5];
  const float* b_f      = (const float*)d_in[6];
  const float* wih_b    = (const float*)d_in[7];
  const float* whh_b    = (const float*)d_in[8];
  const float* b_b      = (const float*)d_in[9];
  const float* linW     = (const float*)d_in[10];
  const float* linb     = (const float*)d_in[11];
  const float* trans    = (const float*)d_in[12];
  float* out = (float*)d_out;

  // workspace: bp 1 MiB | wt 1 MiB | xg 128 MiB | rnn 32 MiB | feats 2.5 MiB
  char* ws = (char*)d_ws;
  __half* bp    = (__half*)ws;
  float*  wt    = (float*)(ws + (1ull << 20));
  __half* xg    = (__half*)(ws + (2ull << 20));
  __half* rnn   = (__half*)(ws + (2ull << 20) + (128ull << 20));
  float*  feats = (float*)(ws + (2ull << 20) + (160ull << 20));

  prep_whh_mfma<<<dim3(256), dim3(256), 0, stream>>>(whh_f, whh_b, bp);
  prep_wih<<<dim3(1024), dim3(256), 0, stream>>>(wih_f, wih_b, wt);
  xg_gemm<<<dim3(4096), dim3(256), 0, stream>>>(word_seq, lengths, embed, wt, b_f, b_b, xg);
  lstm_mfma<<<dim3(8), dim3(512), 0, stream>>>(lengths, bp, xg, rnn);
  feat_gemv<<<dim3(2560), dim3(256), 0, stream>>>(lengths, rnn, linW, linb, feats);
  crf_kernel<<<dim3(64), dim3(64), 0, stream>>>(tags, lengths, trans, feats, out);
}